// Round 7
// baseline (277.786 us; speedup 1.0000x reference)
//
#include <hip/hip_runtime.h>
#include <hip/hip_bf16.h>
#include <math.h>

constexpr int B_  = 4;
constexpr int S_  = 1024;
constexpr int D_  = 512;
constexpr int H_  = 8;
constexpr int DK_ = 64;
constexpr int MROWS_ = B_ * S_;          // 4096
constexpr size_t SZ_ = (size_t)B_ * H_ * S_ * DK_;  // 2M elems per tensor
constexpr size_t WSZ_ = (size_t)D_ * D_;            // 256K elems per weight

typedef __attribute__((ext_vector_type(8))) short bf16x8;
typedef __attribute__((ext_vector_type(4))) float f32x4;

__device__ __forceinline__ float bf2f(unsigned short u) {
  union { unsigned int u; float f; } v; v.u = (unsigned int)u << 16; return v.f;
}
__device__ __forceinline__ unsigned short f2bf(float f) {
  union { float f; unsigned int u; } v; v.f = f;
  unsigned int r = v.u + 0x7FFFu + ((v.u >> 16) & 1u);   // RNE
  return (unsigned short)(r >> 16);
}
// fast round-half-up: 2 VALU ops; used only for MFMA-input P weights
__device__ __forceinline__ unsigned short f2bf_ru(float f) {
  union { float f; unsigned int u; } v; v.f = f;
  return (unsigned short)((v.u + 0x8000u) >> 16);
}

// ---- raw-hardware transcendentals (no libm fixup sequences) ----
__device__ __forceinline__ float ex2(float x) {
#if __has_builtin(__builtin_amdgcn_exp2f)
  return __builtin_amdgcn_exp2f(x);
#else
  float r; asm("v_exp_f32 %0, %1" : "=v"(r) : "v"(x)); return r;
#endif
}
__device__ __forceinline__ float fsqrt_raw(float x) {
#if __has_builtin(__builtin_amdgcn_sqrtf)
  return __builtin_amdgcn_sqrtf(x);
#else
  float r; asm("v_sqrt_f32 %0, %1" : "=v"(r) : "v"(x)); return r;
#endif
}
__device__ __forceinline__ float frcp_raw(float x) {
#if __has_builtin(__builtin_amdgcn_rcpf)
  return __builtin_amdgcn_rcpf(x);
#else
  float r; asm("v_rcp_f32 %0, %1" : "=v"(r) : "v"(x)); return r;
#endif
}

// ---- DPP cross-lane helpers (VALU pipe, no LDS) ----
template <int CTRL>
__device__ __forceinline__ float dpp_mov_f(float x) {
  return __builtin_bit_cast(float,
      __builtin_amdgcn_update_dpp(0, __builtin_bit_cast(int, x), CTRL, 0xF, 0xF, true));
}
// inclusive prefix sum within each 16-lane row
__device__ __forceinline__ float scan16(float v) {
  v += dpp_mov_f<0x111>(v);   // row_shr:1
  v += dpp_mov_f<0x112>(v);   // row_shr:2
  v += dpp_mov_f<0x114>(v);   // row_shr:4
  v += dpp_mov_f<0x118>(v);   // row_shr:8
  return v;
}
// full sum within each 16-lane row (all lanes get result)
__device__ __forceinline__ float red16(float v) {
  v += dpp_mov_f<0x128>(v);   // row_ror:8
  v += dpp_mov_f<0x124>(v);   // row_ror:4
  v += dpp_mov_f<0x122>(v);   // row_ror:2
  v += dpp_mov_f<0x121>(v);   // row_ror:1
  return v;
}
// broadcast lane15 of each 16-lane group: src=(lane&0x10)|0xF per 32-half
__device__ __forceinline__ float bcast15(float v) {
  return __builtin_bit_cast(float,
      __builtin_amdgcn_ds_swizzle(__builtin_bit_cast(int, v), 0x01F0));
}

// async global->LDS 16B/lane; LDS dest is wave-uniform base + lane*16
__device__ __forceinline__ void gll16(const unsigned short* g, unsigned short* l) {
  __builtin_amdgcn_global_load_lds(
      (const __attribute__((address_space(1))) unsigned int*)g,
      (__attribute__((address_space(3))) unsigned int*)l, 16, 0, 0);
}

// ---------------------------------------------------------------------------
// W transpose+convert: W fp32 [k][n] -> Wt bf16 [n][k]. (unchanged)
// ---------------------------------------------------------------------------
struct TpArgs { const float* W[4]; unsigned short* out[4]; };

__global__ __launch_bounds__(256) void wtrans(TpArgs a) {
  const int z = blockIdx.z;
  const float* __restrict__ W = a.W[z];
  unsigned short* __restrict__ out = a.out[z];
  __shared__ float T[64][65];
  const int tid = threadIdx.x;
  const int tx = blockIdx.x & 7, ty = blockIdx.x >> 3;
  const int k0 = ty * 64, n0 = tx * 64;
#pragma unroll
  for (int i = 0; i < 4; ++i) {
    const int idx = tid + i * 256;
    const int r = idx >> 4, c4 = (idx & 15) * 4;
    const float4 w = *(const float4*)&W[(size_t)(k0 + r) * D_ + n0 + c4];
    T[r][c4 + 0] = w.x; T[r][c4 + 1] = w.y; T[r][c4 + 2] = w.z; T[r][c4 + 3] = w.w;
  }
  __syncthreads();
#pragma unroll
  for (int i = 0; i < 4; ++i) {
    const int idx = tid + i * 256;
    const int n = idx >> 4, kc = (idx & 15) * 4;
    ushort4 pk;
    pk.x = f2bf(T[kc + 0][n]); pk.y = f2bf(T[kc + 1][n]);
    pk.z = f2bf(T[kc + 2][n]); pk.w = f2bf(T[kc + 3][n]);
    *(ushort4*)&out[(size_t)(n0 + n) * D_ + k0 + kc] = pk;
  }
}

// ---------------------------------------------------------------------------
// MFMA projection GEMM (R10 form: B via global_load_lds, A reg-staged).
// ---------------------------------------------------------------------------
struct ProjArgs {
  const float* A[6]; const unsigned short* Wt[6]; const float* bias[6];
  unsigned short* out[6]; int vmode[6];
};

__global__ __launch_bounds__(256) void proj_mfma(ProjArgs args) {
  const int z = blockIdx.z;
  const float* __restrict__ A = args.A[z];
  const unsigned short* __restrict__ Wt = args.Wt[z];
  const float* __restrict__ bias = args.bias[z];
  unsigned short* __restrict__ out = args.out[z];
  const int vmode = args.vmode[z];

  __shared__ unsigned short Abuf[128][40];
  __shared__ unsigned short Bbuf[128][32];
  const int tid = threadIdx.x, wv = tid >> 6, lane = tid & 63;
  const int quad = lane >> 4, l16 = lane & 15;
  const int wm = wv >> 1, wn = wv & 1;
  const int n0 = blockIdx.x * 128, m0 = blockIdx.y * 128;

  f32x4 acc[4][4];
#pragma unroll
  for (int i = 0; i < 4; ++i)
#pragma unroll
    for (int j = 0; j < 4; ++j) acc[i][j] = (f32x4){0.f, 0.f, 0.f, 0.f};

  for (int kt = 0; kt < 16; ++kt) {
    const int k0 = kt * 32;
    __syncthreads();
#pragma unroll
    for (int i = 0; i < 2; ++i) {
      const int idx = tid + i * 256;
      const int n = idx >> 2, c = idx & 3;
      gll16(&Wt[(size_t)(n0 + n) * D_ + k0 + c * 8], &Bbuf[n][c * 8]);
    }
#pragma unroll
    for (int i = 0; i < 4; ++i) {
      const int idx = tid + i * 256;
      const int m = idx >> 3, c = idx & 7;
      const float4 av = *(const float4*)&A[(size_t)(m0 + m) * D_ + k0 + c * 4];
      ushort4 p;
      p.x = f2bf(av.x); p.y = f2bf(av.y); p.z = f2bf(av.z); p.w = f2bf(av.w);
      *(ushort4*)&Abuf[m][c * 4] = p;
    }
    __syncthreads();

    bf16x8 af[4], bfr[4];
#pragma unroll
    for (int i = 0; i < 4; ++i) af[i] = *(const bf16x8*)&Abuf[wm * 64 + i * 16 + l16][quad * 8];
#pragma unroll
    for (int j = 0; j < 4; ++j) bfr[j] = *(const bf16x8*)&Bbuf[wn * 64 + j * 16 + l16][quad * 8];
#pragma unroll
    for (int i = 0; i < 4; ++i)
#pragma unroll
      for (int j = 0; j < 4; ++j)
        acc[i][j] = __builtin_amdgcn_mfma_f32_16x16x32_bf16(af[i], bfr[j], acc[i][j], 0, 0, 0);
  }

#pragma unroll
  for (int j = 0; j < 4; ++j) {
    const int col = n0 + wn * 64 + j * 16 + l16;
    const float bv = bias[col];
    const int h = col >> 6, dk = col & 63;
#pragma unroll
    for (int i = 0; i < 4; ++i) {
      const int mbase = m0 + wm * 64 + i * 16 + quad * 4;
      const int b = mbase >> 10;
      if (!vmode) {
#pragma unroll
        for (int r = 0; r < 4; ++r) {
          const int s = (mbase + r) & 1023;
          out[(((size_t)b * H_ + h) * S_ + s) * DK_ + dk] = f2bf(acc[i][j][r] + bv);
        }
      } else {
        const int s = mbase & 1023;
        ushort4 pk;
        pk.x = f2bf(acc[i][j][0] + bv); pk.y = f2bf(acc[i][j][1] + bv);
        pk.z = f2bf(acc[i][j][2] + bv); pk.w = f2bf(acc[i][j][3] + bv);
        *(ushort4*)&out[(((size_t)b * H_ + h) * DK_ + dk) * S_ + s] = pk;
      }
    }
  }
}

// ---------------------------------------------------------------------------
// MFMA output GEMM (R10 form: A and B via global_load_lds).
// ---------------------------------------------------------------------------
struct OutArgs {
  const unsigned short* A[2]; const unsigned short* Wt[2];
  const float* bias[2]; float* out[2];
};

__global__ __launch_bounds__(256) void out_mfma(OutArgs args) {
  const int z = blockIdx.z;
  const unsigned short* __restrict__ A = args.A[z];
  const unsigned short* __restrict__ Wt = args.Wt[z];
  const float* __restrict__ bias = args.bias[z];
  float* __restrict__ out = args.out[z];

  __shared__ unsigned short Abuf[128][32];
  __shared__ unsigned short Bbuf[128][32];
  const int tid = threadIdx.x, wv = tid >> 6, lane = tid & 63;
  const int quad = lane >> 4, l16 = lane & 15;
  const int wm = wv >> 1, wn = wv & 1;
  const int n0 = blockIdx.x * 128, m0 = blockIdx.y * 128;

  f32x4 acc[4][4];
#pragma unroll
  for (int i = 0; i < 4; ++i)
#pragma unroll
    for (int j = 0; j < 4; ++j) acc[i][j] = (f32x4){0.f, 0.f, 0.f, 0.f};

  for (int kt = 0; kt < 16; ++kt) {
    const int k0 = kt * 32;
    __syncthreads();
#pragma unroll
    for (int i = 0; i < 2; ++i) {
      const int idx = tid + i * 256;
      const int m = idx >> 2, c = idx & 3;
      gll16(&A[(size_t)(m0 + m) * D_ + k0 + c * 8], &Abuf[m][c * 8]);
    }
#pragma unroll
    for (int i = 0; i < 2; ++i) {
      const int idx = tid + i * 256;
      const int n = idx >> 2, c = idx & 3;
      gll16(&Wt[(size_t)(n0 + n) * D_ + k0 + c * 8], &Bbuf[n][c * 8]);
    }
    __syncthreads();

    bf16x8 af[4], bfr[4];
#pragma unroll
    for (int i = 0; i < 4; ++i) af[i] = *(const bf16x8*)&Abuf[wm * 64 + i * 16 + l16][quad * 8];
#pragma unroll
    for (int j = 0; j < 4; ++j) bfr[j] = *(const bf16x8*)&Bbuf[wn * 64 + j * 16 + l16][quad * 8];
#pragma unroll
    for (int i = 0; i < 4; ++i)
#pragma unroll
      for (int j = 0; j < 4; ++j)
        acc[i][j] = __builtin_amdgcn_mfma_f32_16x16x32_bf16(af[i], bfr[j], acc[i][j], 0, 0, 0);
  }

#pragma unroll
  for (int j = 0; j < 4; ++j) {
    const int col = n0 + wn * 64 + j * 16 + l16;
    const float bv = bias[col];
#pragma unroll
    for (int i = 0; i < 4; ++i) {
      const int mbase = m0 + wm * 64 + i * 16 + quad * 4;
#pragma unroll
      for (int r = 0; r < 4; ++r)
        out[(size_t)(mbase + r) * D_ + col] = acc[i][j][r] + bv;
    }
  }
}

// ---------------------------------------------------------------------------
// R11 attention: intra-block split-K. One q-tile per 8-wave block; waves 0-3
// (grp 0) handle k-tiles [0,mid), waves 4-7 (grp 1) handle [mid,nt). Pass A
// partials shared via LDS give grp 1 its exact prefix carry (= T0) and both
// groups invT = rcp(T0+T1). Pass B partial oacc/l2 combined through LDS
// (aliasing the dead Ps buffer). Zero instruction duplication vs R8 —
// purely a wave-schedule fix: uniform per-wave work (nt units vs 2nt),
// max block 16 units (vs 32), 4-blocks/CU grid with backfill.
// Grid (bh=32, y=16 [qt=15-y, heavy first], ch=2), block = 512 (8 waves).
// ---------------------------------------------------------------------------
__global__ __launch_bounds__(512) void attn_mfma(
    const unsigned short* __restrict__ qkv, const float* __restrict__ gammas,
    unsigned short* __restrict__ Obase)
{
  __shared__ unsigned short Ps[8][16][72];   // per-wave P tile; aliased as Cmb after pass B
  __shared__ float Tpart[2][64];             // per-group pass-A row sums; Cl2 after pass B

  float* const Cmb = (float*)&Ps[0][0][0];   // [64][65] f32 combine buffer (16.6KB <= 18KB)
  float* const Cl2 = &Tpart[0][0];           // 64 f32 l2 partials (Tpart dead after pass A)

  const int tid = threadIdx.x;
  const int w = tid >> 6, lane = tid & 63, quad = lane >> 4, l16 = lane & 15;
  const int bh = blockIdx.x;
  const int qt = 15 - (int)blockIdx.y;       // heavy-first dispatch
  const int ch = blockIdx.z;
  const int grp = w >> 2;                    // k-split group: 0 -> [0,mid), 1 -> [mid,nt)
  const int wq = w & 3;                      // q-row sub-tile (same rows in both groups)
  const int q0 = qt << 6;
  const int b = bh >> 3, h = bh & 7;

  const int nt = qt + 1;
  const int mid = (nt + 1) >> 1;
  const int t_lo = grp ? mid : 0;
  const int t_hi = grp ? nt : mid;

  constexpr float SC_ = 0.125f * 1.4426950408889634f;   // (1/8)*log2(e)
  constexpr float LOG2E_ = 1.4426950408889634f;

  const unsigned short* Q  = qkv + (size_t)ch * 3 * SZ_ + (size_t)bh * S_ * DK_;
  const unsigned short* K  = qkv + (size_t)ch * 3 * SZ_ + SZ_ + (size_t)bh * S_ * DK_;
  const unsigned short* Vt = qkv + (size_t)ch * 3 * SZ_ + 2 * SZ_ + (size_t)bh * (size_t)DK_ * S_;
  unsigned short* O = Obase + (size_t)ch * SZ_;

  const float g = gammas[h];
  const float gv2 = -(fmaxf(g, 0.f) + log1pf(__expf(-fabsf(g)))) * LOG2E_;  // -softplus*log2e

  // Q fragments, direct from global (held all kernel)
  const unsigned short* Qrow = Q + (size_t)(q0 + wq * 16 + l16) * DK_;
  const bf16x8 qf0 = *(const bf16x8*)(Qrow + quad * 8);
  const bf16x8 qf1 = *(const bf16x8*)(Qrow + 32 + quad * 8);
  const int myrow = q0 + wq * 16 + quad * 4;   // + r
  const int rowb = wq * 16 + quad * 4;         // row index 0..63 within tile

  // ===================== pass A: partial T over own k-range =================
  float Tacc[4] = {0.f, 0.f, 0.f, 0.f};
  for (int kt = t_lo; kt < t_hi; ++kt) {
    f32x4 sa[4];
#pragma unroll
    for (int cb = 0; cb < 4; ++cb) {
      const unsigned short* Kr = K + (size_t)(kt * 64 + cb * 16 + l16) * DK_;
      const bf16x8 kf0 = *(const bf16x8*)(Kr + quad * 8);
      const bf16x8 kf1 = *(const bf16x8*)(Kr + 32 + quad * 8);
      f32x4 a = {0.f, 0.f, 0.f, 0.f};
      a = __builtin_amdgcn_mfma_f32_16x16x32_bf16(qf0, kf0, a, 0, 0, 0);
      a = __builtin_amdgcn_mfma_f32_16x16x32_bf16(qf1, kf1, a, 0, 0, 0);
      sa[cb] = a;
    }
    if (kt == qt) {
#pragma unroll
      for (int cb = 0; cb < 4; ++cb)
#pragma unroll
        for (int r = 0; r < 4; ++r) {
          float e = ex2(sa[cb][r] * SC_);
          if ((kt * 64 + cb * 16 + l16) > (myrow + r)) e = 0.f;
          Tacc[r] += e;
        }
    } else {
#pragma unroll
      for (int cb = 0; cb < 4; ++cb)
#pragma unroll
        for (int r = 0; r < 4; ++r)
          Tacc[r] += ex2(sa[cb][r] * SC_);
    }
  }
  // per-row partial sums -> LDS (16 lanes of each row-group write same value)
#pragma unroll
  for (int r = 0; r < 4; ++r)
    Tpart[grp][rowb + r] = red16(Tacc[r]);
  __syncthreads();

  float invT[4], carry[4];
#pragma unroll
  for (int r = 0; r < 4; ++r) {
    const float T0 = Tpart[0][rowb + r];
    const float T1 = Tpart[1][rowb + r];
    invT[r] = frcp_raw(T0 + T1);
    carry[r] = grp ? T0 : 0.f;    // exact prefix: grp1 starts after grp0's mass
  }

  // ===================== pass B over own k-range ============================
  float l2a[4] = {0.f, 0.f, 0.f, 0.f};
  f32x4 oacc[4];
#pragma unroll
  for (int cb = 0; cb < 4; ++cb) oacc[cb] = (f32x4){0.f, 0.f, 0.f, 0.f};

  for (int kt = t_lo; kt < t_hi; ++kt) {
    // V fragments (B-operand for PV), issue loads early
    bf16x8 vf0[4], vf1[4];
#pragma unroll
    for (int cb = 0; cb < 4; ++cb) {
      const unsigned short* Vr = Vt + (size_t)(cb * 16 + l16) * S_ + kt * 64;
      vf0[cb] = *(const bf16x8*)(Vr + quad * 8);
      vf1[cb] = *(const bf16x8*)(Vr + 32 + quad * 8);
    }

    f32x4 sa[4];
#pragma unroll
    for (int cb = 0; cb < 4; ++cb) {
      const unsigned short* Kr = K + (size_t)(kt * 64 + cb * 16 + l16) * DK_;
      const bf16x8 kf0 = *(const bf16x8*)(Kr + quad * 8);
      const bf16x8 kf1 = *(const bf16x8*)(Kr + 32 + quad * 8);
      f32x4 a = {0.f, 0.f, 0.f, 0.f};
      a = __builtin_amdgcn_mfma_f32_16x16x32_bf16(qf0, kf0, a, 0, 0, 0);
      a = __builtin_amdgcn_mfma_f32_16x16x32_bf16(qf1, kf1, a, 0, 0, 0);
      sa[cb] = a;
    }
    // scale into log2 domain + causal mask
#pragma unroll
    for (int cb = 0; cb < 4; ++cb)
#pragma unroll
      for (int r = 0; r < 4; ++r) sa[cb][r] *= SC_;
    if (kt == qt) {
#pragma unroll
      for (int cb = 0; cb < 4; ++cb)
#pragma unroll
        for (int r = 0; r < 4; ++r)
          if ((kt * 64 + cb * 16 + l16) > (myrow + r)) sa[cb][r] = -1e30f;
    }

#pragma unroll
    for (int r = 0; r < 4; ++r) {
      // unnormalized softmax-1 terms + DPP prefix scan per 16-col group
      float v0 = scan16(ex2(sa[0][r]));
      float v1 = scan16(ex2(sa[1][r]));
      float v2 = scan16(ex2(sa[2][r]));
      float v3 = scan16(ex2(sa[3][r]));
      const float tt0 = bcast15(v0), tt1 = bcast15(v1);
      const float tt2 = bcast15(v2), tt3 = bcast15(v3);
      const float base = carry[r];
      const float p01 = tt0 + tt1, p012 = p01 + tt2;
      const float cum0 = (base + v0) * invT[r];
      const float cum1 = (base + tt0 + v1) * invT[r];
      const float cum2 = (base + p01 + v2) * invT[r];
      const float cum3 = (base + p012 + v3) * invT[r];
      carry[r] = base + p012 + tt3;

      // distance decay e = max(exp2(sqrt(clip((1-cum)*pos)) * gv2), 1e-5)
      const float bpos = (float)(myrow + r) - (float)(kt * 64 + l16);
      float dd, st0, st1, st2, st3;
      dd = fsqrt_raw(fmaxf((1.f - cum0) * bpos, 0.f));
      st0 = sa[0][r] * fmaxf(ex2(dd * gv2), 1e-5f);
      dd = fsqrt_raw(fmaxf((1.f - cum1) * (bpos - 16.f), 0.f));
      st1 = sa[1][r] * fmaxf(ex2(dd * gv2), 1e-5f);
      dd = fsqrt_raw(fmaxf((1.f - cum2) * (bpos - 32.f), 0.f));
      st2 = sa[2][r] * fmaxf(ex2(dd * gv2), 1e-5f);
      dd = fsqrt_raw(fmaxf((1.f - cum3) * (bpos - 48.f), 0.f));
      st3 = sa[3][r] * fmaxf(ex2(dd * gv2), 1e-5f);

      // unnormalized softmax-2 weights (lane-partial l2)
      const float w0 = ex2(st0), w1 = ex2(st1);
      const float w2 = ex2(st2), w3 = ex2(st3);
      l2a[r] += (w0 + w1) + (w2 + w3);
      const int prow = quad * 4 + r;
      Ps[w][prow][ 0 + l16] = f2bf_ru(w0);
      Ps[w][prow][16 + l16] = f2bf_ru(w1);
      Ps[w][prow][32 + l16] = f2bf_ru(w2);
      Ps[w][prow][48 + l16] = f2bf_ru(w3);
    }
    asm volatile("s_waitcnt lgkmcnt(0)" ::: "memory");  // wave-private Ps

    const bf16x8 pf0 = *(const bf16x8*)&Ps[w][l16][quad * 8];
    const bf16x8 pf1 = *(const bf16x8*)&Ps[w][l16][32 + quad * 8];
#pragma unroll
    for (int cb = 0; cb < 4; ++cb) {
      oacc[cb] = __builtin_amdgcn_mfma_f32_16x16x32_bf16(pf0, vf0[cb], oacc[cb], 0, 0, 0);
      oacc[cb] = __builtin_amdgcn_mfma_f32_16x16x32_bf16(pf1, vf1[cb], oacc[cb], 0, 0, 0);
    }
  }

  // ===================== combine (grp1 -> LDS, grp0 adds + writes) ==========
  __syncthreads();   // all pass-B Ps usage complete (Cmb aliases Ps)
  if (grp == 1) {
#pragma unroll
    for (int r = 0; r < 4; ++r) {
      const int row = rowb + r;
      Cl2[row] = red16(l2a[r]);
      Cmb[row * 65 +  0 + l16] = oacc[0][r];
      Cmb[row * 65 + 16 + l16] = oacc[1][r];
      Cmb[row * 65 + 32 + l16] = oacc[2][r];
      Cmb[row * 65 + 48 + l16] = oacc[3][r];
    }
  }
  __syncthreads();
  if (grp == 0) {
#pragma unroll
    for (int r = 0; r < 4; ++r) {
      const int row = rowb + r;
      const float inv = frcp_raw(red16(l2a[r]) + Cl2[row]);
      const int srow = q0 + row;
      const size_t base = ((size_t)b * S_ + srow) * D_ + h * DK_;
      O[base +  0 + l16] = f2bf((oacc[0][r] + Cmb[row * 65 +  0 + l16]) * inv);
      O[base + 16 + l16] = f2bf((oacc[1][r] + Cmb[row * 65 + 16 + l16]) * inv);
      O[base + 32 + l16] = f2bf((oacc[2][r] + Cmb[row * 65 + 32 + l16]) * inv);
      O[base + 48 + l16] = f2bf((oacc[3][r] + Cmb[row * 65 + 48 + l16]) * inv);
    }
  }
}

// ---------------------------------------------------------------------------
// Launch (same 5-kernel plan; attn on the split-K grid).
// ---------------------------------------------------------------------------
extern "C" void kernel_launch(void* const* d_in, const int* in_sizes, int n_in,
                              void* d_out, int out_size, void* d_ws, size_t ws_size,
                              hipStream_t stream) {
  const float* query_mean  = (const float*)d_in[0];
  const float* query_cov   = (const float*)d_in[1];
  const float* key_mean    = (const float*)d_in[2];
  const float* key_cov     = (const float*)d_in[3];
  const float* values_mean = (const float*)d_in[4];
  const float* values_cov  = (const float*)d_in[5];
  const float* Wk_mean = (const float*)d_in[6];
  const float* bk_mean = (const float*)d_in[7];
  const float* Wk_cov  = (const float*)d_in[8];
  const float* bk_cov  = (const float*)d_in[9];
  const float* Wv_mean = (const float*)d_in[10];
  const float* bv_mean = (const float*)d_in[11];
  const float* Wv_cov  = (const float*)d_in[12];
  const float* bv_cov  = (const float*)d_in[13];
  const float* Wo_mean = (const float*)d_in[14];
  const float* bo_mean = (const float*)d_in[15];
  const float* Wo_cov  = (const float*)d_in[16];
  const float* bo_cov  = (const float*)d_in[17];
  const float* gammas  = (const float*)d_in[18];

  unsigned short* qkv  = (unsigned short*)d_ws;
  unsigned short* obuf = qkv + 6 * SZ_;
  unsigned short* Wt4  = (unsigned short*)d_out;       // d_out as scratch
  unsigned short* Wot  = qkv + 2 * SZ_;                // V^T-mean slot, dead after attn
  float* out = (float*)d_out;

  TpArgs t1;
  t1.W[0] = Wk_mean; t1.W[1] = Wv_mean; t1.W[2] = Wk_cov; t1.W[3] = Wv_cov;
  for (int i = 0; i < 4; ++i) t1.out[i] = Wt4 + (size_t)i * WSZ_;
  wtrans<<<dim3(64, 1, 4), 256, 0, stream>>>(t1);

  ProjArgs pa;
  const float* pA[6] = {query_mean, key_mean, values_mean, query_cov, key_cov, values_cov};
  const int   wIdx[6] = {0, 0, 1, 2, 2, 3};
  const float* pb[6] = {bk_mean, bk_mean, bv_mean, bk_cov, bk_cov, bv_cov};
  const int pv[6] = {0, 0, 1, 0, 0, 1};
  for (int i = 0; i < 6; ++i) {
    pa.A[i] = pA[i]; pa.Wt[i] = Wt4 + (size_t)wIdx[i] * WSZ_; pa.bias[i] = pb[i];
    pa.out[i] = qkv + (size_t)i * SZ_; pa.vmode[i] = pv[i];
  }
  proj_mfma<<<dim3(4, 32, 6), 256, 0, stream>>>(pa);

  attn_mfma<<<dim3(32, 16, 2), 512, 0, stream>>>(qkv, gammas, obuf);

  TpArgs t2;
  t2.W[0] = Wo_mean; t2.W[1] = Wo_cov; t2.W[2] = Wo_mean; t2.W[3] = Wo_cov;
  t2.out[0] = Wot; t2.out[1] = Wot + WSZ_; t2.out[2] = Wot; t2.out[3] = Wot + WSZ_;
  wtrans<<<dim3(64, 1, 2), 256, 0, stream>>>(t2);

  OutArgs oa;
  oa.A[0] = obuf;        oa.A[1] = obuf + SZ_;
  oa.Wt[0] = Wot;        oa.Wt[1] = Wot + WSZ_;
  oa.bias[0] = bo_mean;  oa.bias[1] = bo_cov;
  oa.out[0] = out;       oa.out[1] = out + (size_t)MROWS_ * D_;
  out_mfma<<<dim3(4, 32, 2), 256, 0, stream>>>(oa);
}

// Round 8
// 264.976 us; speedup vs baseline: 1.0483x; 1.0483x over previous
//
#include <hip/hip_runtime.h>
#include <hip/hip_bf16.h>
#include <math.h>

constexpr int B_  = 4;
constexpr int S_  = 1024;
constexpr int D_  = 512;
constexpr int H_  = 8;
constexpr int DK_ = 64;
constexpr int MROWS_ = B_ * S_;          // 4096
constexpr size_t SZ_ = (size_t)B_ * H_ * S_ * DK_;  // 2M elems per tensor
constexpr size_t WSZ_ = (size_t)D_ * D_;            // 256K elems per weight

typedef __attribute__((ext_vector_type(8))) short bf16x8;
typedef __attribute__((ext_vector_type(4))) float f32x4;

__device__ __forceinline__ float bf2f(unsigned short u) {
  union { unsigned int u; float f; } v; v.u = (unsigned int)u << 16; return v.f;
}
__device__ __forceinline__ unsigned short f2bf(float f) {
  union { float f; unsigned int u; } v; v.f = f;
  unsigned int r = v.u + 0x7FFFu + ((v.u >> 16) & 1u);   // RNE
  return (unsigned short)(r >> 16);
}
// fast round-half-up: 2 VALU ops; used only for MFMA-input P weights
__device__ __forceinline__ unsigned short f2bf_ru(float f) {
  union { float f; unsigned int u; } v; v.f = f;
  return (unsigned short)((v.u + 0x8000u) >> 16);
}

// ---- raw-hardware transcendentals (no libm fixup sequences) ----
__device__ __forceinline__ float ex2(float x) {
#if __has_builtin(__builtin_amdgcn_exp2f)
  return __builtin_amdgcn_exp2f(x);
#else
  float r; asm("v_exp_f32 %0, %1" : "=v"(r) : "v"(x)); return r;
#endif
}
__device__ __forceinline__ float fsqrt_raw(float x) {
#if __has_builtin(__builtin_amdgcn_sqrtf)
  return __builtin_amdgcn_sqrtf(x);
#else
  float r; asm("v_sqrt_f32 %0, %1" : "=v"(r) : "v"(x)); return r;
#endif
}
__device__ __forceinline__ float frcp_raw(float x) {
#if __has_builtin(__builtin_amdgcn_rcpf)
  return __builtin_amdgcn_rcpf(x);
#else
  float r; asm("v_rcp_f32 %0, %1" : "=v"(r) : "v"(x)); return r;
#endif
}

// ---- DPP cross-lane helpers (VALU pipe, no LDS) ----
template <int CTRL>
__device__ __forceinline__ float dpp_mov_f(float x) {
  return __builtin_bit_cast(float,
      __builtin_amdgcn_update_dpp(0, __builtin_bit_cast(int, x), CTRL, 0xF, 0xF, true));
}
// inclusive prefix sum within each 16-lane row
__device__ __forceinline__ float scan16(float v) {
  v += dpp_mov_f<0x111>(v);   // row_shr:1
  v += dpp_mov_f<0x112>(v);   // row_shr:2
  v += dpp_mov_f<0x114>(v);   // row_shr:4
  v += dpp_mov_f<0x118>(v);   // row_shr:8
  return v;
}
// full sum within each 16-lane row (all lanes get result)
__device__ __forceinline__ float red16(float v) {
  v += dpp_mov_f<0x128>(v);   // row_ror:8
  v += dpp_mov_f<0x124>(v);   // row_ror:4
  v += dpp_mov_f<0x122>(v);   // row_ror:2
  v += dpp_mov_f<0x121>(v);   // row_ror:1
  return v;
}
// broadcast lane15 of each 16-lane group: src=(lane&0x10)|0xF per 32-half
__device__ __forceinline__ float bcast15(float v) {
  return __builtin_bit_cast(float,
      __builtin_amdgcn_ds_swizzle(__builtin_bit_cast(int, v), 0x01F0));
}

// async global->LDS 16B/lane; LDS dest is wave-uniform base + lane*16
__device__ __forceinline__ void gll16(const unsigned short* g, unsigned short* l) {
  __builtin_amdgcn_global_load_lds(
      (const __attribute__((address_space(1))) unsigned int*)g,
      (__attribute__((address_space(3))) unsigned int*)l, 16, 0, 0);
}

// ---------------------------------------------------------------------------
// Activation pre-convert: fp32 [4096][512] -> bf16, once per tensor.
// Removes the 4x-redundant fp32 load+convert from proj_mfma's A staging.
// ---------------------------------------------------------------------------
struct CvtArgs { const float* src[6]; unsigned short* dst; };

__global__ __launch_bounds__(256) void a2bf(CvtArgs a) {
  const int z = blockIdx.z;
  const float* __restrict__ src = a.src[z];
  unsigned short* __restrict__ dst = a.dst + (size_t)z * MROWS_ * D_;
  const int idx = blockIdx.x * 256 + threadIdx.x;   // 65536 threads
#pragma unroll
  for (int i = 0; i < 8; ++i) {
    const size_t j = (size_t)idx + (size_t)i * 65536;   // float4 index
    const float4 v = *(const float4*)&src[j * 4];
    ushort4 p;
    p.x = f2bf(v.x); p.y = f2bf(v.y); p.z = f2bf(v.z); p.w = f2bf(v.w);
    *(ushort4*)&dst[j * 4] = p;
  }
}

// ---------------------------------------------------------------------------
// W transpose+convert: W fp32 [k][n] -> Wt bf16 [n][k]. Now 6 tensors.
// ---------------------------------------------------------------------------
struct TpArgs { const float* W[6]; unsigned short* out[6]; };

__global__ __launch_bounds__(256) void wtrans(TpArgs a) {
  const int z = blockIdx.z;
  const float* __restrict__ W = a.W[z];
  unsigned short* __restrict__ out = a.out[z];
  __shared__ float T[64][65];
  const int tid = threadIdx.x;
  const int tx = blockIdx.x & 7, ty = blockIdx.x >> 3;
  const int k0 = ty * 64, n0 = tx * 64;
#pragma unroll
  for (int i = 0; i < 4; ++i) {
    const int idx = tid + i * 256;
    const int r = idx >> 4, c4 = (idx & 15) * 4;
    const float4 w = *(const float4*)&W[(size_t)(k0 + r) * D_ + n0 + c4];
    T[r][c4 + 0] = w.x; T[r][c4 + 1] = w.y; T[r][c4 + 2] = w.z; T[r][c4 + 3] = w.w;
  }
  __syncthreads();
#pragma unroll
  for (int i = 0; i < 4; ++i) {
    const int idx = tid + i * 256;
    const int n = idx >> 4, kc = (idx & 15) * 4;
    ushort4 pk;
    pk.x = f2bf(T[kc + 0][n]); pk.y = f2bf(T[kc + 1][n]);
    pk.z = f2bf(T[kc + 2][n]); pk.w = f2bf(T[kc + 3][n]);
    *(ushort4*)&out[(size_t)(n0 + n) * D_ + k0 + kc] = pk;
  }
}

// ---------------------------------------------------------------------------
// MFMA projection GEMM. R12: A (pre-converted bf16) AND B both staged via
// global_load_lds -- zero staging VALU (full m97 pattern).
// ---------------------------------------------------------------------------
struct ProjArgs {
  const unsigned short* A[6]; const unsigned short* Wt[6]; const float* bias[6];
  unsigned short* out[6]; int vmode[6];
};

__global__ __launch_bounds__(256) void proj_mfma(ProjArgs args) {
  const int z = blockIdx.z;
  const unsigned short* __restrict__ A = args.A[z];
  const unsigned short* __restrict__ Wt = args.Wt[z];
  const float* __restrict__ bias = args.bias[z];
  unsigned short* __restrict__ out = args.out[z];
  const int vmode = args.vmode[z];

  __shared__ unsigned short Abuf[128][32];
  __shared__ unsigned short Bbuf[128][32];
  const int tid = threadIdx.x, wv = tid >> 6, lane = tid & 63;
  const int quad = lane >> 4, l16 = lane & 15;
  const int wm = wv >> 1, wn = wv & 1;
  const int n0 = blockIdx.x * 128, m0 = blockIdx.y * 128;

  f32x4 acc[4][4];
#pragma unroll
  for (int i = 0; i < 4; ++i)
#pragma unroll
    for (int j = 0; j < 4; ++j) acc[i][j] = (f32x4){0.f, 0.f, 0.f, 0.f};

  for (int kt = 0; kt < 16; ++kt) {
    const int k0 = kt * 32;
    __syncthreads();
#pragma unroll
    for (int i = 0; i < 2; ++i) {
      const int idx = tid + i * 256;
      const int m = idx >> 2, c = idx & 3;
      gll16(&A[(size_t)(m0 + m) * D_ + k0 + c * 8], &Abuf[m][c * 8]);
    }
#pragma unroll
    for (int i = 0; i < 2; ++i) {
      const int idx = tid + i * 256;
      const int n = idx >> 2, c = idx & 3;
      gll16(&Wt[(size_t)(n0 + n) * D_ + k0 + c * 8], &Bbuf[n][c * 8]);
    }
    __syncthreads();

    bf16x8 af[4], bfr[4];
#pragma unroll
    for (int i = 0; i < 4; ++i) af[i] = *(const bf16x8*)&Abuf[wm * 64 + i * 16 + l16][quad * 8];
#pragma unroll
    for (int j = 0; j < 4; ++j) bfr[j] = *(const bf16x8*)&Bbuf[wn * 64 + j * 16 + l16][quad * 8];
#pragma unroll
    for (int i = 0; i < 4; ++i)
#pragma unroll
      for (int j = 0; j < 4; ++j)
        acc[i][j] = __builtin_amdgcn_mfma_f32_16x16x32_bf16(af[i], bfr[j], acc[i][j], 0, 0, 0);
  }

#pragma unroll
  for (int j = 0; j < 4; ++j) {
    const int col = n0 + wn * 64 + j * 16 + l16;
    const float bv = bias[col];
    const int h = col >> 6, dk = col & 63;
#pragma unroll
    for (int i = 0; i < 4; ++i) {
      const int mbase = m0 + wm * 64 + i * 16 + quad * 4;
      const int b = mbase >> 10;
      if (!vmode) {
#pragma unroll
        for (int r = 0; r < 4; ++r) {
          const int s = (mbase + r) & 1023;
          out[(((size_t)b * H_ + h) * S_ + s) * DK_ + dk] = f2bf(acc[i][j][r] + bv);
        }
      } else {
        const int s = mbase & 1023;
        ushort4 pk;
        pk.x = f2bf(acc[i][j][0] + bv); pk.y = f2bf(acc[i][j][1] + bv);
        pk.z = f2bf(acc[i][j][2] + bv); pk.w = f2bf(acc[i][j][3] + bv);
        *(ushort4*)&out[(((size_t)b * H_ + h) * DK_ + dk) * S_ + s] = pk;
      }
    }
  }
}

// ---------------------------------------------------------------------------
// MFMA output GEMM (R10 form: A and B via global_load_lds).
// ---------------------------------------------------------------------------
struct OutArgs {
  const unsigned short* A[2]; const unsigned short* Wt[2];
  const float* bias[2]; float* out[2];
};

__global__ __launch_bounds__(256) void out_mfma(OutArgs args) {
  const int z = blockIdx.z;
  const unsigned short* __restrict__ A = args.A[z];
  const unsigned short* __restrict__ Wt = args.Wt[z];
  const float* __restrict__ bias = args.bias[z];
  float* __restrict__ out = args.out[z];

  __shared__ unsigned short Abuf[128][32];
  __shared__ unsigned short Bbuf[128][32];
  const int tid = threadIdx.x, wv = tid >> 6, lane = tid & 63;
  const int quad = lane >> 4, l16 = lane & 15;
  const int wm = wv >> 1, wn = wv & 1;
  const int n0 = blockIdx.x * 128, m0 = blockIdx.y * 128;

  f32x4 acc[4][4];
#pragma unroll
  for (int i = 0; i < 4; ++i)
#pragma unroll
    for (int j = 0; j < 4; ++j) acc[i][j] = (f32x4){0.f, 0.f, 0.f, 0.f};

  for (int kt = 0; kt < 16; ++kt) {
    const int k0 = kt * 32;
    __syncthreads();
#pragma unroll
    for (int i = 0; i < 2; ++i) {
      const int idx = tid + i * 256;
      const int m = idx >> 2, c = idx & 3;
      gll16(&A[(size_t)(m0 + m) * D_ + k0 + c * 8], &Abuf[m][c * 8]);
    }
#pragma unroll
    for (int i = 0; i < 2; ++i) {
      const int idx = tid + i * 256;
      const int n = idx >> 2, c = idx & 3;
      gll16(&Wt[(size_t)(n0 + n) * D_ + k0 + c * 8], &Bbuf[n][c * 8]);
    }
    __syncthreads();

    bf16x8 af[4], bfr[4];
#pragma unroll
    for (int i = 0; i < 4; ++i) af[i] = *(const bf16x8*)&Abuf[wm * 64 + i * 16 + l16][quad * 8];
#pragma unroll
    for (int j = 0; j < 4; ++j) bfr[j] = *(const bf16x8*)&Bbuf[wn * 64 + j * 16 + l16][quad * 8];
#pragma unroll
    for (int i = 0; i < 4; ++i)
#pragma unroll
      for (int j = 0; j < 4; ++j)
        acc[i][j] = __builtin_amdgcn_mfma_f32_16x16x32_bf16(af[i], bfr[j], acc[i][j], 0, 0, 0);
  }

#pragma unroll
  for (int j = 0; j < 4; ++j) {
    const int col = n0 + wn * 64 + j * 16 + l16;
    const float bv = bias[col];
#pragma unroll
    for (int i = 0; i < 4; ++i) {
      const int mbase = m0 + wm * 64 + i * 16 + quad * 4;
#pragma unroll
      for (int r = 0; r < 4; ++r)
        out[(size_t)(mbase + r) * D_ + col] = acc[i][j][r] + bv;
    }
  }
}

// ---------------------------------------------------------------------------
// R12 attention: exact R8 (100.4us best-known). Raw v_exp/v_sqrt/v_rcp,
// exp2-domain, bcast15 ds_swizzle, paired q-tiles, single Ps + lgkmcnt(0).
// Grid (bh=32, pair=8, ch=2), block = 512 (8 waves).
// ---------------------------------------------------------------------------
__global__ __launch_bounds__(512) void attn_mfma(
    const unsigned short* __restrict__ qkv, const float* __restrict__ gammas,
    unsigned short* __restrict__ Obase)
{
  __shared__ unsigned short Ps[8][16][72];   // per-wave P relayout tile

  const int tid = threadIdx.x;
  const int w = tid >> 6, lane = tid & 63, quad = lane >> 4, l16 = lane & 15;
  const int bh = blockIdx.x;
  const int pair = blockIdx.y;
  const int ch = blockIdx.z;
  const int qt = (w < 4) ? (15 - pair) : pair;
  const int wq = w & 3;
  const int q0 = qt << 6;
  const int b = bh >> 3, h = bh & 7;

  constexpr float SC_ = 0.125f * 1.4426950408889634f;   // (1/8)*log2(e)
  constexpr float LOG2E_ = 1.4426950408889634f;

  const unsigned short* Q  = qkv + (size_t)ch * 3 * SZ_ + (size_t)bh * S_ * DK_;
  const unsigned short* K  = qkv + (size_t)ch * 3 * SZ_ + SZ_ + (size_t)bh * S_ * DK_;
  const unsigned short* Vt = qkv + (size_t)ch * 3 * SZ_ + 2 * SZ_ + (size_t)bh * (size_t)DK_ * S_;
  unsigned short* O = Obase + (size_t)ch * SZ_;

  const float g = gammas[h];
  const float gv2 = -(fmaxf(g, 0.f) + log1pf(__expf(-fabsf(g)))) * LOG2E_;  // -softplus*log2e

  // Q fragments, direct from global (held all kernel)
  const unsigned short* Qrow = Q + (size_t)(q0 + wq * 16 + l16) * DK_;
  const bf16x8 qf0 = *(const bf16x8*)(Qrow + quad * 8);
  const bf16x8 qf1 = *(const bf16x8*)(Qrow + 32 + quad * 8);
  const int myrow = q0 + wq * 16 + quad * 4;   // + r

  // ===================== pass A: T = sum exp2(s*SC) =====================
  float Tacc[4] = {0.f, 0.f, 0.f, 0.f};
  for (int kt = 0; kt <= qt; ++kt) {
    f32x4 sa[4];
#pragma unroll
    for (int cb = 0; cb < 4; ++cb) {
      const unsigned short* Kr = K + (size_t)(kt * 64 + cb * 16 + l16) * DK_;
      const bf16x8 kf0 = *(const bf16x8*)(Kr + quad * 8);
      const bf16x8 kf1 = *(const bf16x8*)(Kr + 32 + quad * 8);
      f32x4 a = {0.f, 0.f, 0.f, 0.f};
      a = __builtin_amdgcn_mfma_f32_16x16x32_bf16(qf0, kf0, a, 0, 0, 0);
      a = __builtin_amdgcn_mfma_f32_16x16x32_bf16(qf1, kf1, a, 0, 0, 0);
      sa[cb] = a;
    }
    if (kt == qt) {
#pragma unroll
      for (int cb = 0; cb < 4; ++cb)
#pragma unroll
        for (int r = 0; r < 4; ++r) {
          float e = ex2(sa[cb][r] * SC_);
          if ((kt * 64 + cb * 16 + l16) > (myrow + r)) e = 0.f;
          Tacc[r] += e;
        }
    } else {
#pragma unroll
      for (int cb = 0; cb < 4; ++cb)
#pragma unroll
        for (int r = 0; r < 4; ++r)
          Tacc[r] += ex2(sa[cb][r] * SC_);
    }
  }
  float invT[4];
#pragma unroll
  for (int r = 0; r < 4; ++r) invT[r] = frcp_raw(red16(Tacc[r]));

  // ===================== pass B =====================
  float carry[4] = {0.f, 0.f, 0.f, 0.f};
  float l2a[4] = {0.f, 0.f, 0.f, 0.f};
  f32x4 oacc[4];
#pragma unroll
  for (int cb = 0; cb < 4; ++cb) oacc[cb] = (f32x4){0.f, 0.f, 0.f, 0.f};

  for (int kt = 0; kt <= qt; ++kt) {
    // V fragments (B-operand for PV), issue loads early
    bf16x8 vf0[4], vf1[4];
#pragma unroll
    for (int cb = 0; cb < 4; ++cb) {
      const unsigned short* Vr = Vt + (size_t)(cb * 16 + l16) * S_ + kt * 64;
      vf0[cb] = *(const bf16x8*)(Vr + quad * 8);
      vf1[cb] = *(const bf16x8*)(Vr + 32 + quad * 8);
    }

    f32x4 sa[4];
#pragma unroll
    for (int cb = 0; cb < 4; ++cb) {
      const unsigned short* Kr = K + (size_t)(kt * 64 + cb * 16 + l16) * DK_;
      const bf16x8 kf0 = *(const bf16x8*)(Kr + quad * 8);
      const bf16x8 kf1 = *(const bf16x8*)(Kr + 32 + quad * 8);
      f32x4 a = {0.f, 0.f, 0.f, 0.f};
      a = __builtin_amdgcn_mfma_f32_16x16x32_bf16(qf0, kf0, a, 0, 0, 0);
      a = __builtin_amdgcn_mfma_f32_16x16x32_bf16(qf1, kf1, a, 0, 0, 0);
      sa[cb] = a;
    }
    // scale into log2 domain + causal mask
#pragma unroll
    for (int cb = 0; cb < 4; ++cb)
#pragma unroll
      for (int r = 0; r < 4; ++r) sa[cb][r] *= SC_;
    if (kt == qt) {
#pragma unroll
      for (int cb = 0; cb < 4; ++cb)
#pragma unroll
        for (int r = 0; r < 4; ++r)
          if ((kt * 64 + cb * 16 + l16) > (myrow + r)) sa[cb][r] = -1e30f;
    }

#pragma unroll
    for (int r = 0; r < 4; ++r) {
      // unnormalized softmax-1 terms + DPP prefix scan per 16-col group
      float v0 = scan16(ex2(sa[0][r]));
      float v1 = scan16(ex2(sa[1][r]));
      float v2 = scan16(ex2(sa[2][r]));
      float v3 = scan16(ex2(sa[3][r]));
      const float tt0 = bcast15(v0), tt1 = bcast15(v1);
      const float tt2 = bcast15(v2), tt3 = bcast15(v3);
      const float base = carry[r];
      const float p01 = tt0 + tt1, p012 = p01 + tt2;
      const float cum0 = (base + v0) * invT[r];
      const float cum1 = (base + tt0 + v1) * invT[r];
      const float cum2 = (base + p01 + v2) * invT[r];
      const float cum3 = (base + p012 + v3) * invT[r];
      carry[r] = base + p012 + tt3;

      // distance decay e = max(exp2(sqrt(clip((1-cum)*pos)) * gv2), 1e-5)
      const float bpos = (float)(myrow + r) - (float)(kt * 64 + l16);
      float dd, st0, st1, st2, st3;
      dd = fsqrt_raw(fmaxf((1.f - cum0) * bpos, 0.f));
      st0 = sa[0][r] * fmaxf(ex2(dd * gv2), 1e-5f);
      dd = fsqrt_raw(fmaxf((1.f - cum1) * (bpos - 16.f), 0.f));
      st1 = sa[1][r] * fmaxf(ex2(dd * gv2), 1e-5f);
      dd = fsqrt_raw(fmaxf((1.f - cum2) * (bpos - 32.f), 0.f));
      st2 = sa[2][r] * fmaxf(ex2(dd * gv2), 1e-5f);
      dd = fsqrt_raw(fmaxf((1.f - cum3) * (bpos - 48.f), 0.f));
      st3 = sa[3][r] * fmaxf(ex2(dd * gv2), 1e-5f);

      // unnormalized softmax-2 weights (lane-partial l2)
      const float w0 = ex2(st0), w1 = ex2(st1);
      const float w2 = ex2(st2), w3 = ex2(st3);
      l2a[r] += (w0 + w1) + (w2 + w3);
      const int prow = quad * 4 + r;
      Ps[w][prow][ 0 + l16] = f2bf_ru(w0);
      Ps[w][prow][16 + l16] = f2bf_ru(w1);
      Ps[w][prow][32 + l16] = f2bf_ru(w2);
      Ps[w][prow][48 + l16] = f2bf_ru(w3);
    }
    asm volatile("s_waitcnt lgkmcnt(0)" ::: "memory");  // wave-private Ps

    const bf16x8 pf0 = *(const bf16x8*)&Ps[w][l16][quad * 8];
    const bf16x8 pf1 = *(const bf16x8*)&Ps[w][l16][32 + quad * 8];
#pragma unroll
    for (int cb = 0; cb < 4; ++cb) {
      oacc[cb] = __builtin_amdgcn_mfma_f32_16x16x32_bf16(pf0, vf0[cb], oacc[cb], 0, 0, 0);
      oacc[cb] = __builtin_amdgcn_mfma_f32_16x16x32_bf16(pf1, vf1[cb], oacc[cb], 0, 0, 0);
    }
  }

  // ---- epilogue ----
#pragma unroll
  for (int r = 0; r < 4; ++r) {
    const float inv = frcp_raw(red16(l2a[r]));
    const int srow = myrow + r;
    const size_t base = ((size_t)b * S_ + srow) * D_ + h * DK_;
    O[base +  0 + l16] = f2bf(oacc[0][r] * inv);
    O[base + 16 + l16] = f2bf(oacc[1][r] * inv);
    O[base + 32 + l16] = f2bf(oacc[2][r] * inv);
    O[base + 48 + l16] = f2bf(oacc[3][r] * inv);
  }
}

// ---------------------------------------------------------------------------
// Launch: a2bf + wtrans(6) -> proj -> attn -> out  (4 serial stages).
// ws map (ushort elems): qkv [0,6SZ) | obuf [6SZ,8SZ) | abf [8SZ,14SZ) |
//                        Wot [14SZ, 14SZ+2WSZ)   (~58 MB total)
// ---------------------------------------------------------------------------
extern "C" void kernel_launch(void* const* d_in, const int* in_sizes, int n_in,
                              void* d_out, int out_size, void* d_ws, size_t ws_size,
                              hipStream_t stream) {
  const float* query_mean  = (const float*)d_in[0];
  const float* query_cov   = (const float*)d_in[1];
  const float* key_mean    = (const float*)d_in[2];
  const float* key_cov     = (const float*)d_in[3];
  const float* values_mean = (const float*)d_in[4];
  const float* values_cov  = (const float*)d_in[5];
  const float* Wk_mean = (const float*)d_in[6];
  const float* bk_mean = (const float*)d_in[7];
  const float* Wk_cov  = (const float*)d_in[8];
  const float* bk_cov  = (const float*)d_in[9];
  const float* Wv_mean = (const float*)d_in[10];
  const float* bv_mean = (const float*)d_in[11];
  const float* Wv_cov  = (const float*)d_in[12];
  const float* bv_cov  = (const float*)d_in[13];
  const float* Wo_mean = (const float*)d_in[14];
  const float* bo_mean = (const float*)d_in[15];
  const float* Wo_cov  = (const float*)d_in[16];
  const float* bo_cov  = (const float*)d_in[17];
  const float* gammas  = (const float*)d_in[18];

  unsigned short* qkv  = (unsigned short*)d_ws;
  unsigned short* obuf = qkv + 6 * SZ_;
  unsigned short* abf  = qkv + 8 * SZ_;               // 6 bf16 activation tensors
  unsigned short* Wot  = qkv + 14 * SZ_;              // 2 transposed Wo weights
  unsigned short* Wt4  = (unsigned short*)d_out;      // d_out as scratch (pre-out)
  float* out = (float*)d_out;

  // weight transposes (all 6 in one launch)
  TpArgs t1;
  t1.W[0] = Wk_mean; t1.W[1] = Wv_mean; t1.W[2] = Wk_cov; t1.W[3] = Wv_cov;
  t1.W[4] = Wo_mean; t1.W[5] = Wo_cov;
  for (int i = 0; i < 4; ++i) t1.out[i] = Wt4 + (size_t)i * WSZ_;
  t1.out[4] = Wot; t1.out[5] = Wot + WSZ_;
  wtrans<<<dim3(64, 1, 6), 256, 0, stream>>>(t1);

  // activation fp32 -> bf16 (once)
  CvtArgs cv;
  cv.src[0] = query_mean; cv.src[1] = key_mean; cv.src[2] = values_mean;
  cv.src[3] = query_cov;  cv.src[4] = key_cov;  cv.src[5] = values_cov;
  cv.dst = abf;
  a2bf<<<dim3(256, 1, 6), 256, 0, stream>>>(cv);

  ProjArgs pa;
  const int   wIdx[6] = {0, 0, 1, 2, 2, 3};
  const float* pb[6] = {bk_mean, bk_mean, bv_mean, bk_cov, bk_cov, bv_cov};
  const int pv[6] = {0, 0, 1, 0, 0, 1};
  for (int i = 0; i < 6; ++i) {
    pa.A[i] = abf + (size_t)i * MROWS_ * D_;
    pa.Wt[i] = Wt4 + (size_t)wIdx[i] * WSZ_; pa.bias[i] = pb[i];
    pa.out[i] = qkv + (size_t)i * SZ_; pa.vmode[i] = pv[i];
  }
  proj_mfma<<<dim3(4, 32, 6), 256, 0, stream>>>(pa);

  attn_mfma<<<dim3(32, 8, 2), 512, 0, stream>>>(qkv, gammas, obuf);

  OutArgs oa;
  oa.A[0] = obuf;        oa.A[1] = obuf + SZ_;
  oa.Wt[0] = Wot;        oa.Wt[1] = Wot + WSZ_;
  oa.bias[0] = bo_mean;  oa.bias[1] = bo_cov;
  oa.out[0] = out;       oa.out[1] = out + (size_t)MROWS_ * D_;
  out_mfma<<<dim3(4, 32, 2), 256, 0, stream>>>(oa);
}